// Round 11
// baseline (463.100 us; speedup 1.0000x reference)
//
#include <hip/hip_runtime.h>
#include <hip/hip_bf16.h>
#include <cstdint>
#include <cstddef>

// Problem constants (match reference)
#define N_NODES  20000
#define N_EDGES  320000
#define E_TOTAL  (N_EDGES + N_NODES)   // with self loops = 340000
#define N_GRAPHS 256
#define F_NODE   11
#define F_TDA    30
#define DIM      128
#define NHEAD    4
#define NLAYER   3
#define NTASK    6
#define NEG_SLOPE 0.2f
#define LN_EPS   1e-5f
#define CSR_CAP  64   // fixed per-node capacity; deg ~ Poisson(17), P(>64) ~ 0

typedef short bf16x8 __attribute__((ext_vector_type(8)));
typedef float f32x4  __attribute__((ext_vector_type(4)));
typedef float f32x2  __attribute__((ext_vector_type(2)));

__device__ inline unsigned short f2b(float f) {
    unsigned int u = __builtin_bit_cast(unsigned int, f);
    u += 0x7fffu + ((u >> 16) & 1u);
    return (unsigned short)(u >> 16);
}
__device__ inline float blo(unsigned int u) { return __builtin_bit_cast(float, u << 16); }
__device__ inline float bhi(unsigned int u) { return __builtin_bit_cast(float, u & 0xffff0000u); }
__device__ inline float b2f(unsigned short b) {
    return __builtin_bit_cast(float, ((unsigned int)b) << 16);
}

// ---------------------------------------------------------------------------
// qprep: [0,768) Wstack cast (k-permuted, 0.25 folded); [768,1152) q vectors;
// [1152,1172) zero degs. Runs BEFORE prep so prep can read q_s/q_d safely.
// ---------------------------------------------------------------------------
__global__ __launch_bounds__(256) void qprep_kernel(const float* __restrict__ w_gat,
                                                    const float* __restrict__ a_src,
                                                    const float* __restrict__ a_dst,
                                                    unsigned short* __restrict__ wt2,
                                                    float* __restrict__ q_s,
                                                    float* __restrict__ q_d,
                                                    int* __restrict__ degs) {
    int bx = blockIdx.x;
    int tid = threadIdx.x;
    if (bx < 768) {
        int i = bx * 256 + tid;              // over 3*128*512
        if (i >= NLAYER * 128 * 512) return;
        int l = i >> 16;
        int rem = i & 65535;
        int jcol = rem >> 9;
        int p = rem & 511;
        int lanep = p >> 3, j8 = p & 7;
        int hp = j8 >> 1, bb = j8 & 1;
        int d = lanep * 2 + bb;
        wt2[i] = f2b(w_gat[(size_t)l * 65536 + (size_t)d * 512 + hp * 128 + jcol] * 0.25f);
    } else if (bx < 1152) {
        int bx2 = bx - 768;                  // over 3*128
        int l = bx2 >> 7, k = bx2 & 127;
        int hh_ = tid >> 6, lane = tid & 63;
        int d0 = lane * 2;
        size_t wb = (size_t)l * 65536 + (size_t)k * 512 + hh_ * 128;
        size_t ab = (size_t)l * 512 + hh_ * 128;
        float ps = w_gat[wb + d0] * a_src[ab + d0] + w_gat[wb + d0 + 1] * a_src[ab + d0 + 1];
        float pd = w_gat[wb + d0] * a_dst[ab + d0] + w_gat[wb + d0 + 1] * a_dst[ab + d0 + 1];
#pragma unroll
        for (int off = 32; off; off >>= 1) { ps += __shfl_xor(ps, off); pd += __shfl_xor(pd, off); }
        if (lane == 0) {
            q_s[(size_t)(l * 128 + k) * 4 + hh_] = ps;
            q_d[(size_t)(l * 128 + k) * 4 + hh_] = pd;
        }
    } else {
        int i0 = (bx - 1152) * 1024 + tid;
#pragma unroll
        for (int r = 0; r < 4; r++) {
            int i = i0 + r * 256;
            if (i < N_NODES) degs[i] = 0;
        }
    }
}

// ---------------------------------------------------------------------------
// prep_proj: fat projection (8 nodes/block) + layer-0 alpha.
// ---------------------------------------------------------------------------
__global__ __launch_bounds__(256) void prep_proj_kernel(const float* __restrict__ x,
                                                        const float* __restrict__ w,
                                                        const float* __restrict__ b,
                                                        unsigned short* __restrict__ h_bf,
                                                        const float* __restrict__ q_s,
                                                        const float* __restrict__ q_d,
                                                        float4* __restrict__ als4,
                                                        float4* __restrict__ ald4) {
    int bx = blockIdx.x;
    int tid = threadIdx.x;
    __shared__ float xr[8][F_NODE];
    __shared__ float vbuf[8][128];
    __shared__ float qs_t[512];
    __shared__ float qd_t[512];
    qs_t[tid] = q_s[tid]; qs_t[256 + tid] = q_s[256 + tid];
    qd_t[tid] = q_d[tid]; qd_t[256 + tid] = q_d[256 + tid];
    if (tid < 8 * F_NODE) {
        int nl = tid / F_NODE, k = tid % F_NODE;
        xr[nl][k] = x[(size_t)(bx * 8 + nl) * F_NODE + k];
    }
    __syncthreads();
    int d = tid & 127;
    int halfsel = tid >> 7;
#pragma unroll
    for (int p = 0; p < 4; p++) {
        int nl = p * 2 + halfsel;
        float acc = b[d];
#pragma unroll
        for (int k = 0; k < F_NODE; k++) acc += xr[nl][k] * w[k * DIM + d];
        float v = fmaxf(acc, 0.f);
        h_bf[(size_t)(bx * 8 + nl) * DIM + d] = f2b(v);
        vbuf[nl][d] = v;
    }
    __syncthreads();
    int wave = tid >> 6, lane = tid & 63;
#pragma unroll
    for (int t = 0; t < 2; t++) {
        int nl = wave * 2 + t;
        int n = bx * 8 + nl;
        float2 v2 = *(const float2*)&vbuf[nl][2 * lane];
        int k4 = 2 * lane * 4;
        float ps[4], pd[4];
#pragma unroll
        for (int hh_ = 0; hh_ < 4; hh_++) {
            ps[hh_] = v2.x * qs_t[k4 + hh_] + v2.y * qs_t[k4 + 4 + hh_];
            pd[hh_] = v2.x * qd_t[k4 + hh_] + v2.y * qd_t[k4 + 4 + hh_];
        }
#pragma unroll
        for (int off = 32; off; off >>= 1) {
#pragma unroll
            for (int hh_ = 0; hh_ < 4; hh_++) {
                ps[hh_] += __shfl_xor(ps[hh_], off);
                pd[hh_] += __shfl_xor(pd[hh_], off);
            }
        }
        if (lane == 0) {
            als4[n] = make_float4(ps[0], ps[1], ps[2], ps[3]);
            ald4[n] = make_float4(pd[0], pd[1], pd[2], pd[3]);
        }
    }
}

// ---------------------------------------------------------------------------
// prep_scat: fixed-capacity CSR scatter, 4 edges/thread. NOT idempotent
// standalone, but the FULL PIPELINE is (qprep re-zeroes degs first).
// ---------------------------------------------------------------------------
__global__ __launch_bounds__(256) void prep_scat_kernel(const int* __restrict__ edge_index,
                                                        int* __restrict__ degs,
                                                        int* __restrict__ csr_src) {
    int base = blockIdx.x * 1024;
    int tid = threadIdx.x;
#pragma unroll
    for (int k = 0; k < 4; k++) {
        int e = base + k * 256 + tid;
        if (e < E_TOTAL) {
            int s, d;
            if (e < N_EDGES) { s = edge_index[e]; d = edge_index[N_EDGES + e]; }
            else             { s = e - N_EDGES;   d = s; }
            int pos = atomicAdd(&degs[d], 1);
            if (pos < CSR_CAP) csr_src[d * CSR_CAP + pos] = s;
        }
    }
}

// ---------------------------------------------------------------------------
// agg3 (verified R8: 13.2 us/rep warm; VALUBusy 81%, Occ 67%, VGPR 32).
// ---------------------------------------------------------------------------
template<int LYR, int REPS>
__global__ __launch_bounds__(256) void agg3_kernel(const unsigned short* __restrict__ h_bf,
                                                   const float4* __restrict__ als4,
                                                   const float4* __restrict__ ald4,
                                                   const int* __restrict__ degs,
                                                   const int* __restrict__ csr_src,
                                                   unsigned short* __restrict__ z) {
    __shared__ __align__(16) float wlds[4][CSR_CAP][4];
    __shared__ unsigned olds[4][CSR_CAP];
    int wave = threadIdx.x >> 6, lane = threadIdx.x & 63;
    int n = blockIdx.x * 4 + wave;
    if (n >= N_NODES) return;

    int deg = degs[n];
    deg = (deg < CSR_CAP) ? deg : CSR_CAP;
    const int* __restrict__ srcp = csr_src + (size_t)n * CSR_CAP;
    const unsigned char* __restrict__ hbase = (const unsigned char*)h_bf;
    float4 ad = ald4[n];
    unsigned lane4 = (unsigned)lane * 4u;

#pragma unroll 1
    for (int rep = 0; rep < REPS; ++rep) {
        // ---- phase 1: lane = edge ----
        float4 w4 = make_float4(0.f, 0.f, 0.f, 0.f);
        unsigned off_ = 0;
        if (lane < deg) {
            int s = srcp[lane];                       // coalesced
            off_ = (unsigned)s * 256u;                // byte offset into h_bf row
            float4 as = als4[s];                      // 16B gather, one per edge
            float v;
            v = as.x + ad.x; v = fmaxf(v, NEG_SLOPE * v); w4.x = __expf(fminf(v, 60.f));
            v = as.y + ad.y; v = fmaxf(v, NEG_SLOPE * v); w4.y = __expf(fminf(v, 60.f));
            v = as.z + ad.z; v = fmaxf(v, NEG_SLOPE * v); w4.z = __expf(fminf(v, 60.f));
            v = as.w + ad.w; v = fmaxf(v, NEG_SLOPE * v); w4.w = __expf(fminf(v, 60.f));
        }
        float lsx = w4.x, lsy = w4.y, lsz = w4.z, lsw = w4.w;
#pragma unroll
        for (int o = 32; o; o >>= 1) {
            lsx += __shfl_xor(lsx, o);
            lsy += __shfl_xor(lsy, o);
            lsz += __shfl_xor(lsz, o);
            lsw += __shfl_xor(lsw, o);
        }
        float ix = 1.f / lsx, iy = 1.f / lsy, iz = 1.f / lsz, iw = 1.f / lsw;
        if (lane < deg) {
            wlds[wave][lane][0] = w4.x * ix;
            wlds[wave][lane][1] = w4.y * iy;
            wlds[wave][lane][2] = w4.z * iz;
            wlds[wave][lane][3] = w4.w * iw;
            olds[wave][lane] = off_;
        }
        // ---- phase 2: gather-FMA ----
        f32x2 acc2[4] = {};
        int e = 0;
        for (; e + 4 <= deg; e += 4) {
            unsigned o0 = olds[wave][e];
            unsigned o1 = olds[wave][e + 1];
            unsigned o2 = olds[wave][e + 2];
            unsigned o3 = olds[wave][e + 3];
            unsigned hv0 = *(const unsigned*)(hbase + o0 + lane4);
            unsigned hv1 = *(const unsigned*)(hbase + o1 + lane4);
            unsigned hv2 = *(const unsigned*)(hbase + o2 + lane4);
            unsigned hv3 = *(const unsigned*)(hbase + o3 + lane4);
            float4 w0 = *(const float4*)&wlds[wave][e][0];
            float4 w1 = *(const float4*)&wlds[wave][e + 1][0];
            float4 w2 = *(const float4*)&wlds[wave][e + 2][0];
            float4 w3 = *(const float4*)&wlds[wave][e + 3][0];
            f32x2 f;
            f.x = blo(hv0); f.y = bhi(hv0);
            acc2[0] += w0.x * f; acc2[1] += w0.y * f; acc2[2] += w0.z * f; acc2[3] += w0.w * f;
            f.x = blo(hv1); f.y = bhi(hv1);
            acc2[0] += w1.x * f; acc2[1] += w1.y * f; acc2[2] += w1.z * f; acc2[3] += w1.w * f;
            f.x = blo(hv2); f.y = bhi(hv2);
            acc2[0] += w2.x * f; acc2[1] += w2.y * f; acc2[2] += w2.z * f; acc2[3] += w2.w * f;
            f.x = blo(hv3); f.y = bhi(hv3);
            acc2[0] += w3.x * f; acc2[1] += w3.y * f; acc2[2] += w3.z * f; acc2[3] += w3.w * f;
        }
        for (; e < deg; e++) {
            unsigned o0 = olds[wave][e];
            unsigned hv0 = *(const unsigned*)(hbase + o0 + lane4);
            float4 w0 = *(const float4*)&wlds[wave][e][0];
            f32x2 f;
            f.x = blo(hv0); f.y = bhi(hv0);
            acc2[0] += w0.x * f; acc2[1] += w0.y * f; acc2[2] += w0.z * f; acc2[3] += w0.w * f;
        }
        // ---- epilogue: pack & store (already normalized) ----
        uint4 pb;
        unsigned int* pc = &pb.x;
#pragma unroll
        for (int hh_ = 0; hh_ < 4; hh_++) {
            pc[hh_] = (unsigned)f2b(acc2[hh_].x) | ((unsigned)f2b(acc2[hh_].y) << 16);
        }
        *(uint4*)(z + (size_t)n * 512 + lane * 8) = pb;
    }
}

// ---------------------------------------------------------------------------
// zgemm v2 (verified, BM=64): out = z[M,512] @ wt2[128,512]^T, fused bias +
// LN + ReLU + bf16 residual + next-layer alpha. 512 thr / 8 waves.
// ---------------------------------------------------------------------------
template<int LYR>
__global__ __launch_bounds__(512) void zgemm_kernel(const unsigned short* __restrict__ z,
                                                    const unsigned short* __restrict__ wt2_l,
                                                    const float* __restrict__ b_gat,
                                                    const float* __restrict__ ln_w,
                                                    const float* __restrict__ ln_b,
                                                    const unsigned short* __restrict__ hb_in,
                                                    unsigned short* __restrict__ hb_out,
                                                    const float* __restrict__ q_s_next,
                                                    const float* __restrict__ q_d_next,
                                                    float4* __restrict__ als4,
                                                    float4* __restrict__ ald4,
                                                    int M) {
    __shared__ __align__(16) unsigned short As[64 * 136];
    __shared__ __align__(16) unsigned short Bs[128 * 136];
    __shared__ float redS[2][4][16];
    __shared__ float redQ[2][4][16];
    __shared__ float redPS[2][4][16][4];
    __shared__ float redPD[2][4][16][4];
    int tid = threadIdx.x;
    int m0 = blockIdx.x << 6;
    int wave = tid >> 6, lane = tid & 63;
    int lr = lane & 15, lg = lane >> 4;
    int msub = wave & 3, nh = wave >> 2;

    const uint4 zero4 = make_uint4(0, 0, 0, 0);
    f32x4 acc[4] = {};
    for (int kc = 0; kc < 4; kc++) {
#pragma unroll
        for (int p = 0; p < 2; p++) {        // A: 64 rows x 16 kg (512 thr)
            int i = p * 512 + tid;
            int row = i >> 4, kg = i & 15;
            int arow = m0 + row;
            uint4 av = (arow < M) ? *(const uint4*)(z + (size_t)arow * 512 + kc * 128 + kg * 8) : zero4;
            *(uint4*)&As[row * 136 + kg * 8] = av;
        }
#pragma unroll
        for (int p = 0; p < 4; p++) {        // B: 128 rows x 16 kg (512 thr)
            int i = p * 512 + tid;
            int row = i >> 4, kg = i & 15;
            uint4 bv = *(const uint4*)(wt2_l + (size_t)row * 512 + kc * 128 + kg * 8);
            *(uint4*)&Bs[row * 136 + kg * 8] = bv;
        }
        __syncthreads();
#pragma unroll
        for (int ks = 0; ks < 4; ks++) {
            bf16x8 af = *(const bf16x8*)&As[(msub * 16 + lr) * 136 + ks * 32 + lg * 8];
#pragma unroll
            for (int nt2 = 0; nt2 < 4; nt2++) {
                int nt = nh * 4 + nt2;
                bf16x8 bf_ = *(const bf16x8*)&Bs[(nt * 16 + lr) * 136 + ks * 32 + lg * 8];
                acc[nt2] = __builtin_amdgcn_mfma_f32_16x16x32_bf16(af, bf_, acc[nt2], 0, 0, 0);
            }
        }
        __syncthreads();
    }

    // ---- epilogue: bias + LN (cross-half LDS reduce) + relu + residual ----
    float bg[4], lnw[4], lnb[4];
#pragma unroll
    for (int nt2 = 0; nt2 < 4; nt2++) {
        int col = nh * 64 + nt2 * 16 + lr;
        bg[nt2] = b_gat[col]; lnw[nt2] = ln_w[col]; lnb[nt2] = ln_b[col];
    }
    const bool do_alpha = (LYR + 1 < NLAYER);
    float4 qs4[4], qd4[4];
    if (do_alpha) {
#pragma unroll
        for (int nt2 = 0; nt2 < 4; nt2++) {
            int col = nh * 64 + nt2 * 16 + lr;
            qs4[nt2] = *(const float4*)(q_s_next + (size_t)col * 4);
            qd4[nt2] = *(const float4*)(q_d_next + (size_t)col * 4);
        }
    }
    float g[4][4];                       // [nt2][r]
#pragma unroll
    for (int nt2 = 0; nt2 < 4; nt2++)
#pragma unroll
        for (int r = 0; r < 4; r++) g[nt2][r] = acc[nt2][r] + bg[nt2];
#pragma unroll
    for (int r = 0; r < 4; r++) {
        float s = 0.f, q = 0.f;
#pragma unroll
        for (int nt2 = 0; nt2 < 4; nt2++) { s += g[nt2][r]; q += g[nt2][r] * g[nt2][r]; }
#pragma unroll
        for (int off = 1; off < 16; off <<= 1) { s += __shfl_xor(s, off); q += __shfl_xor(q, off); }
        if (lr == 0) { redS[nh][msub][lg * 4 + r] = s; redQ[nh][msub][lg * 4 + r] = q; }
    }
    __syncthreads();
    float o[4][4];
#pragma unroll
    for (int r = 0; r < 4; r++) {
        int row = m0 + msub * 16 + lg * 4 + r;
        bool valid = (row < M);
        int ri = lg * 4 + r;
        float mu = (redS[0][msub][ri] + redS[1][msub][ri]) * (1.f / 128.f);
        float qq = (redQ[0][msub][ri] + redQ[1][msub][ri]) * (1.f / 128.f);
        float rstd = rsqrtf(fmaxf(qq - mu * mu, 0.f) + LN_EPS);
#pragma unroll
        for (int nt2 = 0; nt2 < 4; nt2++) {
            int col = nh * 64 + nt2 * 16 + lr;
            float hv = valid ? b2f(hb_in[(size_t)row * 128 + col]) : 0.f;
            o[nt2][r] = fmaxf((g[nt2][r] - mu) * rstd * lnw[nt2] + lnb[nt2], 0.f) + hv;
            if (valid) hb_out[(size_t)row * 128 + col] = f2b(o[nt2][r]);
        }
    }
    if (do_alpha) {
        float ps[4][4] = {}, pd[4][4] = {};   // [r][h]
#pragma unroll
        for (int r = 0; r < 4; r++)
#pragma unroll
            for (int nt2 = 0; nt2 < 4; nt2++) {
                ps[r][0] += o[nt2][r] * qs4[nt2].x; pd[r][0] += o[nt2][r] * qd4[nt2].x;
                ps[r][1] += o[nt2][r] * qs4[nt2].y; pd[r][1] += o[nt2][r] * qd4[nt2].y;
                ps[r][2] += o[nt2][r] * qs4[nt2].z; pd[r][2] += o[nt2][r] * qd4[nt2].z;
                ps[r][3] += o[nt2][r] * qs4[nt2].w; pd[r][3] += o[nt2][r] * qd4[nt2].w;
            }
#pragma unroll
        for (int r = 0; r < 4; r++)
#pragma unroll
            for (int off = 1; off < 16; off <<= 1)
#pragma unroll
                for (int hh_ = 0; hh_ < 4; hh_++) {
                    ps[r][hh_] += __shfl_xor(ps[r][hh_], off);
                    pd[r][hh_] += __shfl_xor(pd[r][hh_], off);
                }
        if (lr == 0) {
#pragma unroll
            for (int r = 0; r < 4; r++)
#pragma unroll
                for (int hh_ = 0; hh_ < 4; hh_++) {
                    redPS[nh][msub][lg * 4 + r][hh_] = ps[r][hh_];
                    redPD[nh][msub][lg * 4 + r][hh_] = pd[r][hh_];
                }
        }
        __syncthreads();
        if (nh == 0 && lr == 0) {
#pragma unroll
            for (int r = 0; r < 4; r++) {
                int row = m0 + msub * 16 + lg * 4 + r;
                int ri = lg * 4 + r;
                if (row < M) {
                    als4[row] = make_float4(redPS[0][msub][ri][0] + redPS[1][msub][ri][0],
                                            redPS[0][msub][ri][1] + redPS[1][msub][ri][1],
                                            redPS[0][msub][ri][2] + redPS[1][msub][ri][2],
                                            redPS[0][msub][ri][3] + redPS[1][msub][ri][3]);
                    ald4[row] = make_float4(redPD[0][msub][ri][0] + redPD[1][msub][ri][0],
                                            redPD[0][msub][ri][1] + redPD[1][msub][ri][1],
                                            redPD[0][msub][ri][2] + redPD[1][msub][ri][2],
                                            redPD[0][msub][ri][3] + redPD[1][msub][ri][3]);
                }
            }
        }
    }
}

// ---------------------------------------------------------------------------
// pool4: per-graph pooling split 4 ways — block (g,q4) computes partial
// sum/max over its quarter of graph g's nodes.
// ---------------------------------------------------------------------------
__device__ int lower_bound_dev(const int* a, int n, int v) {
    int lo = 0, hi = n;
    while (lo < hi) { int mid = (lo + hi) >> 1; if (a[mid] < v) lo = mid + 1; else hi = mid; }
    return lo;
}

__global__ __launch_bounds__(256) void pool4_kernel(const unsigned short* __restrict__ h,
                                                    const int* __restrict__ batch,
                                                    float* __restrict__ pool_ws) {
    int g = blockIdx.x >> 2, q4 = blockIdx.x & 3;
    int tid = threadIdx.x;
    __shared__ int bounds[2];
    __shared__ float psum[2][128];
    __shared__ float pmax[2][128];
    if (tid < 2) bounds[tid] = lower_bound_dev(batch, N_NODES, g + tid);
    __syncthreads();
    int lo = bounds[0], hi = bounds[1];
    int cnt = hi - lo;
    int per = (cnt + 3) >> 2;
    int beg = lo + q4 * per;
    int end = min(beg + per, hi);
    int rq = tid >> 7, d = tid & 127;
    float s = 0.f, m = -1e30f;
    for (int i = beg + rq; i < end; i += 2) {
        float v = b2f(h[(size_t)i * DIM + d]);
        s += v; m = fmaxf(m, v);
    }
    psum[rq][d] = s; pmax[rq][d] = m;
    __syncthreads();
    if (tid < 128) {
        float S = psum[0][d] + psum[1][d];
        float M = fmaxf(pmax[0][d], pmax[1][d]);
        pool_ws[(((size_t)g * 4 + q4) * 2 + 0) * 128 + d] = S;
        pool_ws[(((size_t)g * 4 + q4) * 2 + 1) * 128 + d] = M;
    }
}

// ---------------------------------------------------------------------------
// tail: per-graph MLP tail; pooling phase reads the 4 partials from pool_ws.
// ---------------------------------------------------------------------------
__global__ __launch_bounds__(512) void tail_kernel(
    const float* __restrict__ pool_ws, const int* __restrict__ batch,
    const float* __restrict__ tda,
    const float* __restrict__ w_t1, const float* __restrict__ b_t1,
    const float* __restrict__ w_t2, const float* __restrict__ b_t2,
    const float* __restrict__ w_sh1, const float* __restrict__ b_sh1,
    const float* __restrict__ w_sh2, const float* __restrict__ b_sh2,
    const float* __restrict__ w_h1, const float* __restrict__ b_h1,
    const float* __restrict__ w_h2, const float* __restrict__ b_h2,
    float* __restrict__ out) {
    __shared__ int bounds[2];
    __shared__ float comb[320];
    __shared__ float tr[F_TDA];
    __shared__ float t1[64];
    __shared__ float s1o[256];
    __shared__ float s2o[128];
    __shared__ float prods[NTASK * 64];
    int g = blockIdx.x, tid = threadIdx.x;

    if (tid < 2) bounds[tid] = lower_bound_dev(batch, N_NODES, g + tid);
    if (tid >= 2 && tid - 2 < F_TDA) tr[tid - 2] = tda[g * F_TDA + (tid - 2)];
    __syncthreads();
    int cnt = bounds[1] - bounds[0];
    if (tid < 128) {
        float S = 0.f, M = -1e30f;
#pragma unroll
        for (int q4 = 0; q4 < 4; q4++) {
            S += pool_ws[(((size_t)g * 4 + q4) * 2 + 0) * 128 + tid];
            M = fmaxf(M, pool_ws[(((size_t)g * 4 + q4) * 2 + 1) * 128 + tid]);
        }
        comb[tid] = S / fmaxf((float)cnt, 1.f);
        comb[128 + tid] = (cnt > 0) ? M : 0.f;
    } else if (tid >= 128 && tid < 192) {
        int j = tid - 128;
        float a = b_t1[j];
#pragma unroll
        for (int k = 0; k < F_TDA; k++) a += tr[k] * w_t1[k * 64 + j];
        t1[j] = fmaxf(a, 0.f);
    }
    __syncthreads();
    if (tid < 64) {
        float a = b_t2[tid];
#pragma unroll
        for (int k = 0; k < 64; k++) a += t1[k] * w_t2[k * 64 + tid];
        comb[256 + tid] = fmaxf(a, 0.f);
    }
    __syncthreads();
    if (tid < 256) {
        float a = b_sh1[tid];
        for (int k = 0; k < 320; k++) a += comb[k] * w_sh1[k * 256 + tid];
        s1o[tid] = fmaxf(a, 0.f);
    }
    __syncthreads();
    if (tid < 128) {
        float a = b_sh2[tid];
        for (int k = 0; k < 256; k++) a += s1o[k] * w_sh2[k * 128 + tid];
        s2o[tid] = fmaxf(a, 0.f);
    }
    __syncthreads();
    if (tid < NTASK * 64) {
        int t = tid >> 6, k = tid & 63;
        float a = b_h1[t * 64 + k];
#pragma unroll 16
        for (int dd = 0; dd < 128; dd++) a += s2o[dd] * w_h1[(size_t)t * 8192 + dd * 64 + k];
        prods[tid] = fmaxf(a, 0.f) * w_h2[t * 64 + k];
    }
    __syncthreads();
    if (tid < NTASK) {
        float p = b_h2[tid];
#pragma unroll 16
        for (int k = 0; k < 64; k++) p += prods[tid * 64 + k];
        out[tid * 256 + g] = p;
    }
}

// ---------------------------------------------------------------------------
extern "C" void kernel_launch(void* const* d_in, const int* in_sizes, int n_in,
                              void* d_out, int out_size, void* d_ws, size_t ws_size,
                              hipStream_t stream) {
    const float* x        = (const float*)d_in[0];
    const int*   edge_idx = (const int*)  d_in[1];
    const int*   batch    = (const int*)  d_in[2];
    const float* tda      = (const float*)d_in[3];
    const float* w_in     = (const float*)d_in[4];
    const float* b_in     = (const float*)d_in[5];
    const float* w_gat    = (const float*)d_in[6];
    const float* a_src    = (const float*)d_in[7];
    const float* a_dst    = (const float*)d_in[8];
    const float* b_gat    = (const float*)d_in[9];
    const float* ln_w     = (const float*)d_in[10];
    const float* ln_b     = (const float*)d_in[11];
    const float* w_tda1   = (const float*)d_in[12];
    const float* b_tda1   = (const float*)d_in[13];
    const float* w_tda2   = (const float*)d_in[14];
    const float* b_tda2   = (const float*)d_in[15];
    const float* w_sh1    = (const float*)d_in[16];
    const float* b_sh1    = (const float*)d_in[17];
    const float* w_sh2    = (const float*)d_in[18];
    const float* b_sh2    = (const float*)d_in[19];
    const float* w_h1     = (const float*)d_in[20];
    const float* b_h1     = (const float*)d_in[21];
    const float* w_h2     = (const float*)d_in[22];
    const float* b_h2     = (const float*)d_in[23];
    float* out = (float*)d_out;

    size_t off = 0;
    auto alloc = [&](size_t bytes) -> void* {
        void* p = (char*)d_ws + off;
        off += (bytes + 255) & ~(size_t)255;
        return p;
    };
    unsigned short* hb_a   = (unsigned short*)alloc((size_t)N_NODES * DIM * 2);
    unsigned short* hb_b   = (unsigned short*)alloc((size_t)N_NODES * DIM * 2);
    unsigned short* z      = (unsigned short*)alloc((size_t)N_NODES * 512 * 2);
    unsigned short* wt2    = (unsigned short*)alloc((size_t)NLAYER * 128 * 512 * 2);
    float*          q_s    = (float*)alloc((size_t)NLAYER * 128 * 4 * 4);
    float*          q_d    = (float*)alloc((size_t)NLAYER * 128 * 4 * 4);
    float4*         als4   = (float4*)alloc((size_t)N_NODES * 16);
    float4*         ald4   = (float4*)alloc((size_t)N_NODES * 16);
    int*            degs   = (int*)  alloc((size_t)N_NODES * 4);
    int*            csrsrc = (int*)  alloc((size_t)N_NODES * CSR_CAP * 4);
    float*          poolws = (float*)alloc((size_t)N_GRAPHS * 4 * 2 * 128 * 4);

    // DIAGNOSTIC (R11): run the ENTIRE pipeline twice. The full sequence is
    // idempotent as a unit (qprep re-zeroes degs; prep_proj recomputes from
    // pure inputs; everything downstream is deterministic given inputs; CSR
    // slot permutation only perturbs fp summation order, << tolerance).
    // Slope calibration: dur(x2) = fixed + 2*S, dur(x1)=280.8 = fixed + S
    //   -> S = dur2 - 280.8 (true kernel+gap time), fixed = 2*280.8 - dur2
    // Separates H1 (large fixed harness overhead in timed window) from
    // H2 (warm-rep-biased kernel estimates; kernels really cost ~280).
    for (int pipe = 0; pipe < 2; ++pipe) {
        qprep_kernel<<<1172, 256, 0, stream>>>(w_gat, a_src, a_dst, wt2, q_s, q_d, degs);

        prep_proj_kernel<<<2500, 256, 0, stream>>>(x, w_in, b_in, hb_a, q_s, q_d, als4, ald4);
        int sb = (E_TOTAL + 1023) / 1024;   // 333
        prep_scat_kernel<<<sb, 256, 0, stream>>>(edge_idx, degs, csrsrc);

        int ab = (N_NODES + 3) / 4;
        int gb = (N_NODES + 63) / 64;        // 313 blocks (BM=64, verified v2)
        // layer 0: hb_a -> hb_b
        agg3_kernel<0, 1><<<ab, 256, 0, stream>>>(hb_a, als4, ald4, degs, csrsrc, z);
        zgemm_kernel<0><<<gb, 512, 0, stream>>>(z, wt2,
            b_gat, ln_w, ln_b, hb_a, hb_b, q_s + 512, q_d + 512, als4, ald4, N_NODES);
        // layer 1: hb_b -> hb_a
        agg3_kernel<1, 1><<<ab, 256, 0, stream>>>(hb_b, als4, ald4, degs, csrsrc, z);
        zgemm_kernel<1><<<gb, 512, 0, stream>>>(z, wt2 + 65536,
            b_gat + DIM, ln_w + DIM, ln_b + DIM, hb_b, hb_a, q_s + 1024, q_d + 1024,
            als4, ald4, N_NODES);
        // layer 2: hb_a -> hb_b
        agg3_kernel<2, 1><<<ab, 256, 0, stream>>>(hb_a, als4, ald4, degs, csrsrc, z);
        zgemm_kernel<2><<<gb, 512, 0, stream>>>(z, wt2 + 131072,
            b_gat + 2 * DIM, ln_w + 2 * DIM, ln_b + 2 * DIM, hb_a, hb_b,
            nullptr, nullptr, als4, ald4, N_NODES);

        pool4_kernel<<<N_GRAPHS * 4, 256, 0, stream>>>(hb_b, batch, poolws);
        tail_kernel<<<N_GRAPHS, 512, 0, stream>>>(
            poolws, batch, tda, w_tda1, b_tda1, w_tda2, b_tda2,
            w_sh1, b_sh1, w_sh2, b_sh2, w_h1, b_h1, w_h2, b_h2, out);
    }
}

// Round 12
// 363.037 us; speedup vs baseline: 1.2756x; 1.2756x over previous
//
#include <hip/hip_runtime.h>
#include <hip/hip_bf16.h>
#include <cstdint>
#include <cstddef>

// Problem constants (match reference)
#define N_NODES  20000
#define N_EDGES  320000
#define E_TOTAL  (N_EDGES + N_NODES)   // with self loops = 340000
#define N_GRAPHS 256
#define F_NODE   11
#define F_TDA    30
#define DIM      128
#define NHEAD    4
#define NLAYER   3
#define NTASK    6
#define NEG_SLOPE 0.2f
#define LN_EPS   1e-5f
#define CSR_CAP  64   // fixed per-node capacity; deg ~ Poisson(17), P(>64) ~ 0

typedef short bf16x8 __attribute__((ext_vector_type(8)));
typedef float f32x4  __attribute__((ext_vector_type(4)));
typedef float f32x2  __attribute__((ext_vector_type(2)));

__device__ inline unsigned short f2b(float f) {
    unsigned int u = __builtin_bit_cast(unsigned int, f);
    u += 0x7fffu + ((u >> 16) & 1u);
    return (unsigned short)(u >> 16);
}
__device__ inline float blo(unsigned int u) { return __builtin_bit_cast(float, u << 16); }
__device__ inline float bhi(unsigned int u) { return __builtin_bit_cast(float, u & 0xffff0000u); }
__device__ inline float b2f(unsigned short b) {
    return __builtin_bit_cast(float, ((unsigned int)b) << 16);
}

// ---------------------------------------------------------------------------
// qprep: [0,768) Wstack cast (k-permuted, 0.25 folded); [768,1152) q vectors;
// [1152,1172) zero degs. Runs BEFORE prep so prep can read q_s/q_d safely.
// ---------------------------------------------------------------------------
__global__ __launch_bounds__(256) void qprep_kernel(const float* __restrict__ w_gat,
                                                    const float* __restrict__ a_src,
                                                    const float* __restrict__ a_dst,
                                                    unsigned short* __restrict__ wt2,
                                                    float* __restrict__ q_s,
                                                    float* __restrict__ q_d,
                                                    int* __restrict__ degs) {
    int bx = blockIdx.x;
    int tid = threadIdx.x;
    if (bx < 768) {
        int i = bx * 256 + tid;              // over 3*128*512
        if (i >= NLAYER * 128 * 512) return;
        int l = i >> 16;
        int rem = i & 65535;
        int jcol = rem >> 9;
        int p = rem & 511;
        int lanep = p >> 3, j8 = p & 7;
        int hp = j8 >> 1, bb = j8 & 1;
        int d = lanep * 2 + bb;
        wt2[i] = f2b(w_gat[(size_t)l * 65536 + (size_t)d * 512 + hp * 128 + jcol] * 0.25f);
    } else if (bx < 1152) {
        int bx2 = bx - 768;                  // over 3*128
        int l = bx2 >> 7, k = bx2 & 127;
        int hh_ = tid >> 6, lane = tid & 63;
        int d0 = lane * 2;
        size_t wb = (size_t)l * 65536 + (size_t)k * 512 + hh_ * 128;
        size_t ab = (size_t)l * 512 + hh_ * 128;
        float ps = w_gat[wb + d0] * a_src[ab + d0] + w_gat[wb + d0 + 1] * a_src[ab + d0 + 1];
        float pd = w_gat[wb + d0] * a_dst[ab + d0] + w_gat[wb + d0 + 1] * a_dst[ab + d0 + 1];
#pragma unroll
        for (int off = 32; off; off >>= 1) { ps += __shfl_xor(ps, off); pd += __shfl_xor(pd, off); }
        if (lane == 0) {
            q_s[(size_t)(l * 128 + k) * 4 + hh_] = ps;
            q_d[(size_t)(l * 128 + k) * 4 + hh_] = pd;
        }
    } else {
        int i0 = (bx - 1152) * 1024 + tid;
#pragma unroll
        for (int r = 0; r < 4; r++) {
            int i = i0 + r * 256;
            if (i < N_NODES) degs[i] = 0;
        }
    }
}

// ---------------------------------------------------------------------------
// prep_proj: fat projection (8 nodes/block) + layer-0 alpha.
// ---------------------------------------------------------------------------
__global__ __launch_bounds__(256) void prep_proj_kernel(const float* __restrict__ x,
                                                        const float* __restrict__ w,
                                                        const float* __restrict__ b,
                                                        unsigned short* __restrict__ h_bf,
                                                        const float* __restrict__ q_s,
                                                        const float* __restrict__ q_d,
                                                        float4* __restrict__ als4,
                                                        float4* __restrict__ ald4) {
    int bx = blockIdx.x;
    int tid = threadIdx.x;
    __shared__ float xr[8][F_NODE];
    __shared__ float vbuf[8][128];
    __shared__ float qs_t[512];
    __shared__ float qd_t[512];
    qs_t[tid] = q_s[tid]; qs_t[256 + tid] = q_s[256 + tid];
    qd_t[tid] = q_d[tid]; qd_t[256 + tid] = q_d[256 + tid];
    if (tid < 8 * F_NODE) {
        int nl = tid / F_NODE, k = tid % F_NODE;
        xr[nl][k] = x[(size_t)(bx * 8 + nl) * F_NODE + k];
    }
    __syncthreads();
    int d = tid & 127;
    int halfsel = tid >> 7;
#pragma unroll
    for (int p = 0; p < 4; p++) {
        int nl = p * 2 + halfsel;
        float acc = b[d];
#pragma unroll
        for (int k = 0; k < F_NODE; k++) acc += xr[nl][k] * w[k * DIM + d];
        float v = fmaxf(acc, 0.f);
        h_bf[(size_t)(bx * 8 + nl) * DIM + d] = f2b(v);
        vbuf[nl][d] = v;
    }
    __syncthreads();
    int wave = tid >> 6, lane = tid & 63;
#pragma unroll
    for (int t = 0; t < 2; t++) {
        int nl = wave * 2 + t;
        int n = bx * 8 + nl;
        float2 v2 = *(const float2*)&vbuf[nl][2 * lane];
        int k4 = 2 * lane * 4;
        float ps[4], pd[4];
#pragma unroll
        for (int hh_ = 0; hh_ < 4; hh_++) {
            ps[hh_] = v2.x * qs_t[k4 + hh_] + v2.y * qs_t[k4 + 4 + hh_];
            pd[hh_] = v2.x * qd_t[k4 + hh_] + v2.y * qd_t[k4 + 4 + hh_];
        }
#pragma unroll
        for (int off = 32; off; off >>= 1) {
#pragma unroll
            for (int hh_ = 0; hh_ < 4; hh_++) {
                ps[hh_] += __shfl_xor(ps[hh_], off);
                pd[hh_] += __shfl_xor(pd[hh_], off);
            }
        }
        if (lane == 0) {
            als4[n] = make_float4(ps[0], ps[1], ps[2], ps[3]);
            ald4[n] = make_float4(pd[0], pd[1], pd[2], pd[3]);
        }
    }
}

// ---------------------------------------------------------------------------
// prep_scat: fixed-capacity CSR scatter, 4 edges/thread. NOT idempotent.
// ---------------------------------------------------------------------------
__global__ __launch_bounds__(256) void prep_scat_kernel(const int* __restrict__ edge_index,
                                                        int* __restrict__ degs,
                                                        int* __restrict__ csr_src) {
    int base = blockIdx.x * 1024;
    int tid = threadIdx.x;
#pragma unroll
    for (int k = 0; k < 4; k++) {
        int e = base + k * 256 + tid;
        if (e < E_TOTAL) {
            int s, d;
            if (e < N_EDGES) { s = edge_index[e]; d = edge_index[N_EDGES + e]; }
            else             { s = e - N_EDGES;   d = s; }
            int pos = atomicAdd(&degs[d], 1);
            if (pos < CSR_CAP) csr_src[d * CSR_CAP + pos] = s;
        }
    }
}

// ---------------------------------------------------------------------------
// agg3 (verified R8: 13.2 us/rep warm; VALUBusy 81%, Occ 67%, VGPR 32).
// Phase 1 (lane = edge): exps + butterfly sum + pre-divide -> LDS.
// Phase 2 (per edge): uniform ds_reads + 1 global load + 4 pk_fma.
// ---------------------------------------------------------------------------
template<int LYR, int REPS>
__global__ __launch_bounds__(256) void agg3_kernel(const unsigned short* __restrict__ h_bf,
                                                   const float4* __restrict__ als4,
                                                   const float4* __restrict__ ald4,
                                                   const int* __restrict__ degs,
                                                   const int* __restrict__ csr_src,
                                                   unsigned short* __restrict__ z) {
    __shared__ __align__(16) float wlds[4][CSR_CAP][4];
    __shared__ unsigned olds[4][CSR_CAP];
    int wave = threadIdx.x >> 6, lane = threadIdx.x & 63;
    int n = blockIdx.x * 4 + wave;
    if (n >= N_NODES) return;

    int deg = degs[n];
    deg = (deg < CSR_CAP) ? deg : CSR_CAP;
    const int* __restrict__ srcp = csr_src + (size_t)n * CSR_CAP;
    const unsigned char* __restrict__ hbase = (const unsigned char*)h_bf;
    float4 ad = ald4[n];
    unsigned lane4 = (unsigned)lane * 4u;

#pragma unroll 1
    for (int rep = 0; rep < REPS; ++rep) {
        // ---- phase 1: lane = edge ----
        float4 w4 = make_float4(0.f, 0.f, 0.f, 0.f);
        unsigned off_ = 0;
        if (lane < deg) {
            int s = srcp[lane];                       // coalesced
            off_ = (unsigned)s * 256u;                // byte offset into h_bf row
            float4 as = als4[s];                      // 16B gather, one per edge
            float v;
            v = as.x + ad.x; v = fmaxf(v, NEG_SLOPE * v); w4.x = __expf(fminf(v, 60.f));
            v = as.y + ad.y; v = fmaxf(v, NEG_SLOPE * v); w4.y = __expf(fminf(v, 60.f));
            v = as.z + ad.z; v = fmaxf(v, NEG_SLOPE * v); w4.z = __expf(fminf(v, 60.f));
            v = as.w + ad.w; v = fmaxf(v, NEG_SLOPE * v); w4.w = __expf(fminf(v, 60.f));
        }
        float lsx = w4.x, lsy = w4.y, lsz = w4.z, lsw = w4.w;
#pragma unroll
        for (int o = 32; o; o >>= 1) {
            lsx += __shfl_xor(lsx, o);
            lsy += __shfl_xor(lsy, o);
            lsz += __shfl_xor(lsz, o);
            lsw += __shfl_xor(lsw, o);
        }
        float ix = 1.f / lsx, iy = 1.f / lsy, iz = 1.f / lsz, iw = 1.f / lsw;
        if (lane < deg) {
            wlds[wave][lane][0] = w4.x * ix;
            wlds[wave][lane][1] = w4.y * iy;
            wlds[wave][lane][2] = w4.z * iz;
            wlds[wave][lane][3] = w4.w * iw;
            olds[wave][lane] = off_;
        }
        // ---- phase 2: gather-FMA ----
        f32x2 acc2[4] = {};
        int e = 0;
        for (; e + 4 <= deg; e += 4) {
            unsigned o0 = olds[wave][e];
            unsigned o1 = olds[wave][e + 1];
            unsigned o2 = olds[wave][e + 2];
            unsigned o3 = olds[wave][e + 3];
            unsigned hv0 = *(const unsigned*)(hbase + o0 + lane4);
            unsigned hv1 = *(const unsigned*)(hbase + o1 + lane4);
            unsigned hv2 = *(const unsigned*)(hbase + o2 + lane4);
            unsigned hv3 = *(const unsigned*)(hbase + o3 + lane4);
            float4 w0 = *(const float4*)&wlds[wave][e][0];
            float4 w1 = *(const float4*)&wlds[wave][e + 1][0];
            float4 w2 = *(const float4*)&wlds[wave][e + 2][0];
            float4 w3 = *(const float4*)&wlds[wave][e + 3][0];
            f32x2 f;
            f.x = blo(hv0); f.y = bhi(hv0);
            acc2[0] += w0.x * f; acc2[1] += w0.y * f; acc2[2] += w0.z * f; acc2[3] += w0.w * f;
            f.x = blo(hv1); f.y = bhi(hv1);
            acc2[0] += w1.x * f; acc2[1] += w1.y * f; acc2[2] += w1.z * f; acc2[3] += w1.w * f;
            f.x = blo(hv2); f.y = bhi(hv2);
            acc2[0] += w2.x * f; acc2[1] += w2.y * f; acc2[2] += w2.z * f; acc2[3] += w2.w * f;
            f.x = blo(hv3); f.y = bhi(hv3);
            acc2[0] += w3.x * f; acc2[1] += w3.y * f; acc2[2] += w3.z * f; acc2[3] += w3.w * f;
        }
        for (; e < deg; e++) {
            unsigned o0 = olds[wave][e];
            unsigned hv0 = *(const unsigned*)(hbase + o0 + lane4);
            float4 w0 = *(const float4*)&wlds[wave][e][0];
            f32x2 f;
            f.x = blo(hv0); f.y = bhi(hv0);
            acc2[0] += w0.x * f; acc2[1] += w0.y * f; acc2[2] += w0.z * f; acc2[3] += w0.w * f;
        }
        // ---- epilogue: pack & store (already normalized) ----
        uint4 pb;
        unsigned int* pc = &pb.x;
#pragma unroll
        for (int hh_ = 0; hh_ < 4; hh_++) {
            pc[hh_] = (unsigned)f2b(acc2[hh_].x) | ((unsigned)f2b(acc2[hh_].y) << 16);
        }
        *(uint4*)(z + (size_t)n * 512 + lane * 8) = pb;
    }
}

// ---------------------------------------------------------------------------
// zgemm v4 (R11): direct-from-L2 GEMM — NO LDS staging, NO main-loop
// barriers. R9 lesson: staging bytes are invariant to tiling (every M-tile
// needs all of B), and R5 counters showed the block is staging+barrier-
// dominated (VALUBusy 10%, MfmaUtil 7%). Working set (z-tile 65 KB + B
// 131 KB) is L2-resident, so each wave loads A and B fragments (16 B/lane)
// straight into MFMA registers. B re-read 4x per block (msub waves share
// nh) = 164 MB L2 traffic/layer ~ 4.8 us @ 34.5 TB/s — cheaper than the
// removed serialization. Addressing identical to the staged path (same
// qprep k-permutation); epilogue unchanged. LDS drops to ~5 KB (reduces).
// ---------------------------------------------------------------------------
template<int LYR>
__global__ __launch_bounds__(512) void zgemm_kernel(const unsigned short* __restrict__ z,
                                                    const unsigned short* __restrict__ wt2_l,
                                                    const float* __restrict__ b_gat,
                                                    const float* __restrict__ ln_w,
                                                    const float* __restrict__ ln_b,
                                                    const unsigned short* __restrict__ hb_in,
                                                    unsigned short* __restrict__ hb_out,
                                                    const float* __restrict__ q_s_next,
                                                    const float* __restrict__ q_d_next,
                                                    float4* __restrict__ als4,
                                                    float4* __restrict__ ald4,
                                                    int M) {
    __shared__ float redS[2][4][16];
    __shared__ float redQ[2][4][16];
    __shared__ float redPS[2][4][16][4];
    __shared__ float redPD[2][4][16][4];
    int tid = threadIdx.x;
    int m0 = blockIdx.x << 6;
    int wave = tid >> 6, lane = tid & 63;
    int lr = lane & 15, lg = lane >> 4;
    int msub = wave & 3, nh = wave >> 2;

    int arow = m0 + msub * 16 + lr;                  // this lane's A row
    bool arow_ok = (arow < M);
    const unsigned short* __restrict__ aptr = z + (size_t)arow * 512 + lg * 8;
    const unsigned short* __restrict__ bbase = wt2_l + (size_t)(nh * 64 + lr) * 512 + lg * 8;

    const bf16x8 zero8 = {};
    f32x4 acc[4] = {};
#pragma unroll
    for (int kc = 0; kc < 4; kc++) {
#pragma unroll
        for (int ks = 0; ks < 4; ks++) {
            int ko = kc * 128 + ks * 32;
            bf16x8 af = arow_ok ? *(const bf16x8*)(aptr + ko) : zero8;
#pragma unroll
            for (int nt2 = 0; nt2 < 4; nt2++) {
                // B row = (nh*4+nt2)*16 + lr = nh*64 + nt2*16 + lr
                bf16x8 bf_ = *(const bf16x8*)(bbase + (size_t)nt2 * 16 * 512 + ko);
                acc[nt2] = __builtin_amdgcn_mfma_f32_16x16x32_bf16(af, bf_, acc[nt2], 0, 0, 0);
            }
        }
    }

    // ---- epilogue: bias + LN (cross-half LDS reduce) + relu + residual ----
    float bg[4], lnw[4], lnb[4];
#pragma unroll
    for (int nt2 = 0; nt2 < 4; nt2++) {
        int col = nh * 64 + nt2 * 16 + lr;
        bg[nt2] = b_gat[col]; lnw[nt2] = ln_w[col]; lnb[nt2] = ln_b[col];
    }
    const bool do_alpha = (LYR + 1 < NLAYER);
    float4 qs4[4], qd4[4];
    if (do_alpha) {
#pragma unroll
        for (int nt2 = 0; nt2 < 4; nt2++) {
            int col = nh * 64 + nt2 * 16 + lr;
            qs4[nt2] = *(const float4*)(q_s_next + (size_t)col * 4);
            qd4[nt2] = *(const float4*)(q_d_next + (size_t)col * 4);
        }
    }
    float g[4][4];                       // [nt2][r]
#pragma unroll
    for (int nt2 = 0; nt2 < 4; nt2++)
#pragma unroll
        for (int r = 0; r < 4; r++) g[nt2][r] = acc[nt2][r] + bg[nt2];
#pragma unroll
    for (int r = 0; r < 4; r++) {
        float s = 0.f, q = 0.f;
#pragma unroll
        for (int nt2 = 0; nt2 < 4; nt2++) { s += g[nt2][r]; q += g[nt2][r] * g[nt2][r]; }
#pragma unroll
        for (int off = 1; off < 16; off <<= 1) { s += __shfl_xor(s, off); q += __shfl_xor(q, off); }
        if (lr == 0) { redS[nh][msub][lg * 4 + r] = s; redQ[nh][msub][lg * 4 + r] = q; }
    }
    __syncthreads();
    float o[4][4];
#pragma unroll
    for (int r = 0; r < 4; r++) {
        int row = m0 + msub * 16 + lg * 4 + r;
        bool valid = (row < M);
        int ri = lg * 4 + r;
        float mu = (redS[0][msub][ri] + redS[1][msub][ri]) * (1.f / 128.f);
        float qq = (redQ[0][msub][ri] + redQ[1][msub][ri]) * (1.f / 128.f);
        float rstd = rsqrtf(fmaxf(qq - mu * mu, 0.f) + LN_EPS);
#pragma unroll
        for (int nt2 = 0; nt2 < 4; nt2++) {
            int col = nh * 64 + nt2 * 16 + lr;
            float hv = valid ? b2f(hb_in[(size_t)row * 128 + col]) : 0.f;
            o[nt2][r] = fmaxf((g[nt2][r] - mu) * rstd * lnw[nt2] + lnb[nt2], 0.f) + hv;
            if (valid) hb_out[(size_t)row * 128 + col] = f2b(o[nt2][r]);
        }
    }
    if (do_alpha) {
        float ps[4][4] = {}, pd[4][4] = {};   // [r][h]
#pragma unroll
        for (int r = 0; r < 4; r++)
#pragma unroll
            for (int nt2 = 0; nt2 < 4; nt2++) {
                ps[r][0] += o[nt2][r] * qs4[nt2].x; pd[r][0] += o[nt2][r] * qd4[nt2].x;
                ps[r][1] += o[nt2][r] * qs4[nt2].y; pd[r][1] += o[nt2][r] * qd4[nt2].y;
                ps[r][2] += o[nt2][r] * qs4[nt2].z; pd[r][2] += o[nt2][r] * qd4[nt2].z;
                ps[r][3] += o[nt2][r] * qs4[nt2].w; pd[r][3] += o[nt2][r] * qd4[nt2].w;
            }
#pragma unroll
        for (int r = 0; r < 4; r++)
#pragma unroll
            for (int off = 1; off < 16; off <<= 1)
#pragma unroll
                for (int hh_ = 0; hh_ < 4; hh_++) {
                    ps[r][hh_] += __shfl_xor(ps[r][hh_], off);
                    pd[r][hh_] += __shfl_xor(pd[r][hh_], off);
                }
        if (lr == 0) {
#pragma unroll
            for (int r = 0; r < 4; r++)
#pragma unroll
                for (int hh_ = 0; hh_ < 4; hh_++) {
                    redPS[nh][msub][lg * 4 + r][hh_] = ps[r][hh_];
                    redPD[nh][msub][lg * 4 + r][hh_] = pd[r][hh_];
                }
        }
        __syncthreads();
        if (nh == 0 && lr == 0) {
#pragma unroll
            for (int r = 0; r < 4; r++) {
                int row = m0 + msub * 16 + lg * 4 + r;
                int ri = lg * 4 + r;
                if (row < M) {
                    als4[row] = make_float4(redPS[0][msub][ri][0] + redPS[1][msub][ri][0],
                                            redPS[0][msub][ri][1] + redPS[1][msub][ri][1],
                                            redPS[0][msub][ri][2] + redPS[1][msub][ri][2],
                                            redPS[0][msub][ri][3] + redPS[1][msub][ri][3]);
                    ald4[row] = make_float4(redPD[0][msub][ri][0] + redPD[1][msub][ri][0],
                                            redPD[0][msub][ri][1] + redPD[1][msub][ri][1],
                                            redPD[0][msub][ri][2] + redPD[1][msub][ri][2],
                                            redPD[0][msub][ri][3] + redPD[1][msub][ri][3]);
                }
            }
        }
    }
}

// ---------------------------------------------------------------------------
// pool4: per-graph pooling split 4 ways — block (g,q4) computes partial
// sum/max over its quarter of graph g's nodes.
// ---------------------------------------------------------------------------
__device__ int lower_bound_dev(const int* a, int n, int v) {
    int lo = 0, hi = n;
    while (lo < hi) { int mid = (lo + hi) >> 1; if (a[mid] < v) lo = mid + 1; else hi = mid; }
    return lo;
}

__global__ __launch_bounds__(256) void pool4_kernel(const unsigned short* __restrict__ h,
                                                    const int* __restrict__ batch,
                                                    float* __restrict__ pool_ws) {
    int g = blockIdx.x >> 2, q4 = blockIdx.x & 3;
    int tid = threadIdx.x;
    __shared__ int bounds[2];
    __shared__ float psum[2][128];
    __shared__ float pmax[2][128];
    if (tid < 2) bounds[tid] = lower_bound_dev(batch, N_NODES, g + tid);
    __syncthreads();
    int lo = bounds[0], hi = bounds[1];
    int cnt = hi - lo;
    int per = (cnt + 3) >> 2;
    int beg = lo + q4 * per;
    int end = min(beg + per, hi);
    int rq = tid >> 7, d = tid & 127;
    float s = 0.f, m = -1e30f;
    for (int i = beg + rq; i < end; i += 2) {
        float v = b2f(h[(size_t)i * DIM + d]);
        s += v; m = fmaxf(m, v);
    }
    psum[rq][d] = s; pmax[rq][d] = m;
    __syncthreads();
    if (tid < 128) {
        float S = psum[0][d] + psum[1][d];
        float M = fmaxf(pmax[0][d], pmax[1][d]);
        pool_ws[(((size_t)g * 4 + q4) * 2 + 0) * 128 + d] = S;
        pool_ws[(((size_t)g * 4 + q4) * 2 + 1) * 128 + d] = M;
    }
}

// ---------------------------------------------------------------------------
// tail: per-graph MLP tail; pooling phase reads the 4 partials from pool_ws.
// ---------------------------------------------------------------------------
__global__ __launch_bounds__(512) void tail_kernel(
    const float* __restrict__ pool_ws, const int* __restrict__ batch,
    const float* __restrict__ tda,
    const float* __restrict__ w_t1, const float* __restrict__ b_t1,
    const float* __restrict__ w_t2, const float* __restrict__ b_t2,
    const float* __restrict__ w_sh1, const float* __restrict__ b_sh1,
    const float* __restrict__ w_sh2, const float* __restrict__ b_sh2,
    const float* __restrict__ w_h1, const float* __restrict__ b_h1,
    const float* __restrict__ w_h2, const float* __restrict__ b_h2,
    float* __restrict__ out) {
    __shared__ int bounds[2];
    __shared__ float comb[320];
    __shared__ float tr[F_TDA];
    __shared__ float t1[64];
    __shared__ float s1o[256];
    __shared__ float s2o[128];
    __shared__ float prods[NTASK * 64];
    int g = blockIdx.x, tid = threadIdx.x;

    if (tid < 2) bounds[tid] = lower_bound_dev(batch, N_NODES, g + tid);
    if (tid >= 2 && tid - 2 < F_TDA) tr[tid - 2] = tda[g * F_TDA + (tid - 2)];
    __syncthreads();
    int cnt = bounds[1] - bounds[0];
    if (tid < 128) {
        float S = 0.f, M = -1e30f;
#pragma unroll
        for (int q4 = 0; q4 < 4; q4++) {
            S += pool_ws[(((size_t)g * 4 + q4) * 2 + 0) * 128 + tid];
            M = fmaxf(M, pool_ws[(((size_t)g * 4 + q4) * 2 + 1) * 128 + tid]);
        }
        comb[tid] = S / fmaxf((float)cnt, 1.f);
        comb[128 + tid] = (cnt > 0) ? M : 0.f;
    } else if (tid >= 128 && tid < 192) {
        int j = tid - 128;
        float a = b_t1[j];
#pragma unroll
        for (int k = 0; k < F_TDA; k++) a += tr[k] * w_t1[k * 64 + j];
        t1[j] = fmaxf(a, 0.f);
    }
    __syncthreads();
    if (tid < 64) {
        float a = b_t2[tid];
#pragma unroll
        for (int k = 0; k < 64; k++) a += t1[k] * w_t2[k * 64 + tid];
        comb[256 + tid] = fmaxf(a, 0.f);
    }
    __syncthreads();
    if (tid < 256) {
        float a = b_sh1[tid];
        for (int k = 0; k < 320; k++) a += comb[k] * w_sh1[k * 256 + tid];
        s1o[tid] = fmaxf(a, 0.f);
    }
    __syncthreads();
    if (tid < 128) {
        float a = b_sh2[tid];
        for (int k = 0; k < 256; k++) a += s1o[k] * w_sh2[k * 128 + tid];
        s2o[tid] = fmaxf(a, 0.f);
    }
    __syncthreads();
    if (tid < NTASK * 64) {
        int t = tid >> 6, k = tid & 63;
        float a = b_h1[t * 64 + k];
#pragma unroll 16
        for (int dd = 0; dd < 128; dd++) a += s2o[dd] * w_h1[(size_t)t * 8192 + dd * 64 + k];
        prods[tid] = fmaxf(a, 0.f) * w_h2[t * 64 + k];
    }
    __syncthreads();
    if (tid < NTASK) {
        float p = b_h2[tid];
#pragma unroll 16
        for (int k = 0; k < 64; k++) p += prods[tid * 64 + k];
        out[tid * 256 + g] = p;
    }
}

// ---------------------------------------------------------------------------
extern "C" void kernel_launch(void* const* d_in, const int* in_sizes, int n_in,
                              void* d_out, int out_size, void* d_ws, size_t ws_size,
                              hipStream_t stream) {
    const float* x        = (const float*)d_in[0];
    const int*   edge_idx = (const int*)  d_in[1];
    const int*   batch    = (const int*)  d_in[2];
    const float* tda      = (const float*)d_in[3];
    const float* w_in     = (const float*)d_in[4];
    const float* b_in     = (const float*)d_in[5];
    const float* w_gat    = (const float*)d_in[6];
    const float* a_src    = (const float*)d_in[7];
    const float* a_dst    = (const float*)d_in[8];
    const float* b_gat    = (const float*)d_in[9];
    const float* ln_w     = (const float*)d_in[10];
    const float* ln_b     = (const float*)d_in[11];
    const float* w_tda1   = (const float*)d_in[12];
    const float* b_tda1   = (const float*)d_in[13];
    const float* w_tda2   = (const float*)d_in[14];
    const float* b_tda2   = (const float*)d_in[15];
    const float* w_sh1    = (const float*)d_in[16];
    const float* b_sh1    = (const float*)d_in[17];
    const float* w_sh2    = (const float*)d_in[18];
    const float* b_sh2    = (const float*)d_in[19];
    const float* w_h1     = (const float*)d_in[20];
    const float* b_h1     = (const float*)d_in[21];
    const float* w_h2     = (const float*)d_in[22];
    const float* b_h2     = (const float*)d_in[23];
    float* out = (float*)d_out;

    size_t off = 0;
    auto alloc = [&](size_t bytes) -> void* {
        void* p = (char*)d_ws + off;
        off += (bytes + 255) & ~(size_t)255;
        return p;
    };
    unsigned short* hb_a   = (unsigned short*)alloc((size_t)N_NODES * DIM * 2);
    unsigned short* hb_b   = (unsigned short*)alloc((size_t)N_NODES * DIM * 2);
    unsigned short* z      = (unsigned short*)alloc((size_t)N_NODES * 512 * 2);
    unsigned short* wt2    = (unsigned short*)alloc((size_t)NLAYER * 128 * 512 * 2);
    float*          q_s    = (float*)alloc((size_t)NLAYER * 128 * 4 * 4);
    float*          q_d    = (float*)alloc((size_t)NLAYER * 128 * 4 * 4);
    float4*         als4   = (float4*)alloc((size_t)N_NODES * 16);
    float4*         ald4   = (float4*)alloc((size_t)N_NODES * 16);
    int*            degs   = (int*)  alloc((size_t)N_NODES * 4);
    int*            csrsrc = (int*)  alloc((size_t)N_NODES * CSR_CAP * 4);
    float*          poolws = (float*)alloc((size_t)N_GRAPHS * 4 * 2 * 128 * 4);

    // qprep also zeroes degs (blocks 1152..1171) — no separate memset
    qprep_kernel<<<1172, 256, 0, stream>>>(w_gat, a_src, a_dst, wt2, q_s, q_d, degs);

    prep_proj_kernel<<<2500, 256, 0, stream>>>(x, w_in, b_in, hb_a, q_s, q_d, als4, ald4);
    int sb = (E_TOTAL + 1023) / 1024;   // 333
    prep_scat_kernel<<<sb, 256, 0, stream>>>(edge_idx, degs, csrsrc);

    int ab = (N_NODES + 3) / 4;
    int gb = (N_NODES + 63) / 64;        // 313 blocks (BM=64)
    // layer 0: hb_a -> hb_b
    agg3_kernel<0, 1><<<ab, 256, 0, stream>>>(hb_a, als4, ald4, degs, csrsrc, z);
    zgemm_kernel<0><<<gb, 512, 0, stream>>>(z, wt2,
        b_gat, ln_w, ln_b, hb_a, hb_b, q_s + 512, q_d + 512, als4, ald4, N_NODES);
    // layer 1: hb_b -> hb_a
    agg3_kernel<1, 1><<<ab, 256, 0, stream>>>(hb_b, als4, ald4, degs, csrsrc, z);
    zgemm_kernel<1><<<gb, 512, 0, stream>>>(z, wt2 + 65536,
        b_gat + DIM, ln_w + DIM, ln_b + DIM, hb_b, hb_a, q_s + 1024, q_d + 1024,
        als4, ald4, N_NODES);
    // layer 2: hb_a -> hb_b
    agg3_kernel<2, 1><<<ab, 256, 0, stream>>>(hb_a, als4, ald4, degs, csrsrc, z);
    zgemm_kernel<2><<<gb, 512, 0, stream>>>(z, wt2 + 131072,
        b_gat + 2 * DIM, ln_w + 2 * DIM, ln_b + 2 * DIM, hb_a, hb_b,
        nullptr, nullptr, als4, ald4, N_NODES);

    pool4_kernel<<<N_GRAPHS * 4, 256, 0, stream>>>(hb_b, batch, poolws);
    tail_kernel<<<N_GRAPHS, 512, 0, stream>>>(
        poolws, batch, tda, w_tda1, b_tda1, w_tda2, b_tda2,
        w_sh1, b_sh1, w_sh2, b_sh2, w_h1, b_h1, w_h2, b_h2, out);
}

// Round 13
// 283.956 us; speedup vs baseline: 1.6309x; 1.2785x over previous
//
#include <hip/hip_runtime.h>
#include <hip/hip_bf16.h>
#include <cstdint>
#include <cstddef>

// Problem constants (match reference)
#define N_NODES  20000
#define N_EDGES  320000
#define E_TOTAL  (N_EDGES + N_NODES)   // with self loops = 340000
#define N_GRAPHS 256
#define F_NODE   11
#define F_TDA    30
#define DIM      128
#define NHEAD    4
#define NLAYER   3
#define NTASK    6
#define NEG_SLOPE 0.2f
#define LN_EPS   1e-5f
#define CSR_CAP  64   // fixed per-node capacity; deg ~ Poisson(17), P(>64) ~ 0

typedef short bf16x8 __attribute__((ext_vector_type(8)));
typedef float f32x4  __attribute__((ext_vector_type(4)));
typedef float f32x2  __attribute__((ext_vector_type(2)));

__device__ inline unsigned short f2b(float f) {
    unsigned int u = __builtin_bit_cast(unsigned int, f);
    u += 0x7fffu + ((u >> 16) & 1u);
    return (unsigned short)(u >> 16);
}
__device__ inline float blo(unsigned int u) { return __builtin_bit_cast(float, u << 16); }
__device__ inline float bhi(unsigned int u) { return __builtin_bit_cast(float, u & 0xffff0000u); }
__device__ inline float b2f(unsigned short b) {
    return __builtin_bit_cast(float, ((unsigned int)b) << 16);
}

// ---------------------------------------------------------------------------
// qprep: [0,768) Wstack cast (k-permuted, 0.25 folded); [768,1152) q vectors;
// [1152,1172) zero degs. Runs BEFORE prep so prep can read q_s/q_d safely.
// ---------------------------------------------------------------------------
__global__ __launch_bounds__(256) void qprep_kernel(const float* __restrict__ w_gat,
                                                    const float* __restrict__ a_src,
                                                    const float* __restrict__ a_dst,
                                                    unsigned short* __restrict__ wt2,
                                                    float* __restrict__ q_s,
                                                    float* __restrict__ q_d,
                                                    int* __restrict__ degs) {
    int bx = blockIdx.x;
    int tid = threadIdx.x;
    if (bx < 768) {
        int i = bx * 256 + tid;              // over 3*128*512
        if (i >= NLAYER * 128 * 512) return;
        int l = i >> 16;
        int rem = i & 65535;
        int jcol = rem >> 9;
        int p = rem & 511;
        int lanep = p >> 3, j8 = p & 7;
        int hp = j8 >> 1, bb = j8 & 1;
        int d = lanep * 2 + bb;
        wt2[i] = f2b(w_gat[(size_t)l * 65536 + (size_t)d * 512 + hp * 128 + jcol] * 0.25f);
    } else if (bx < 1152) {
        int bx2 = bx - 768;                  // over 3*128
        int l = bx2 >> 7, k = bx2 & 127;
        int hh_ = tid >> 6, lane = tid & 63;
        int d0 = lane * 2;
        size_t wb = (size_t)l * 65536 + (size_t)k * 512 + hh_ * 128;
        size_t ab = (size_t)l * 512 + hh_ * 128;
        float ps = w_gat[wb + d0] * a_src[ab + d0] + w_gat[wb + d0 + 1] * a_src[ab + d0 + 1];
        float pd = w_gat[wb + d0] * a_dst[ab + d0] + w_gat[wb + d0 + 1] * a_dst[ab + d0 + 1];
#pragma unroll
        for (int off = 32; off; off >>= 1) { ps += __shfl_xor(ps, off); pd += __shfl_xor(pd, off); }
        if (lane == 0) {
            q_s[(size_t)(l * 128 + k) * 4 + hh_] = ps;
            q_d[(size_t)(l * 128 + k) * 4 + hh_] = pd;
        }
    } else {
        int i0 = (bx - 1152) * 1024 + tid;
#pragma unroll
        for (int r = 0; r < 4; r++) {
            int i = i0 + r * 256;
            if (i < N_NODES) degs[i] = 0;
        }
    }
}

// ---------------------------------------------------------------------------
// prep_proj: fat projection (8 nodes/block) + layer-0 alpha.
// ---------------------------------------------------------------------------
__global__ __launch_bounds__(256) void prep_proj_kernel(const float* __restrict__ x,
                                                        const float* __restrict__ w,
                                                        const float* __restrict__ b,
                                                        unsigned short* __restrict__ h_bf,
                                                        const float* __restrict__ q_s,
                                                        const float* __restrict__ q_d,
                                                        float4* __restrict__ als4,
                                                        float4* __restrict__ ald4) {
    int bx = blockIdx.x;
    int tid = threadIdx.x;
    __shared__ float xr[8][F_NODE];
    __shared__ float vbuf[8][128];
    __shared__ float qs_t[512];
    __shared__ float qd_t[512];
    qs_t[tid] = q_s[tid]; qs_t[256 + tid] = q_s[256 + tid];
    qd_t[tid] = q_d[tid]; qd_t[256 + tid] = q_d[256 + tid];
    if (tid < 8 * F_NODE) {
        int nl = tid / F_NODE, k = tid % F_NODE;
        xr[nl][k] = x[(size_t)(bx * 8 + nl) * F_NODE + k];
    }
    __syncthreads();
    int d = tid & 127;
    int halfsel = tid >> 7;
#pragma unroll
    for (int p = 0; p < 4; p++) {
        int nl = p * 2 + halfsel;
        float acc = b[d];
#pragma unroll
        for (int k = 0; k < F_NODE; k++) acc += xr[nl][k] * w[k * DIM + d];
        float v = fmaxf(acc, 0.f);
        h_bf[(size_t)(bx * 8 + nl) * DIM + d] = f2b(v);
        vbuf[nl][d] = v;
    }
    __syncthreads();
    int wave = tid >> 6, lane = tid & 63;
#pragma unroll
    for (int t = 0; t < 2; t++) {
        int nl = wave * 2 + t;
        int n = bx * 8 + nl;
        float2 v2 = *(const float2*)&vbuf[nl][2 * lane];
        int k4 = 2 * lane * 4;
        float ps[4], pd[4];
#pragma unroll
        for (int hh_ = 0; hh_ < 4; hh_++) {
            ps[hh_] = v2.x * qs_t[k4 + hh_] + v2.y * qs_t[k4 + 4 + hh_];
            pd[hh_] = v2.x * qd_t[k4 + hh_] + v2.y * qd_t[k4 + 4 + hh_];
        }
#pragma unroll
        for (int off = 32; off; off >>= 1) {
#pragma unroll
            for (int hh_ = 0; hh_ < 4; hh_++) {
                ps[hh_] += __shfl_xor(ps[hh_], off);
                pd[hh_] += __shfl_xor(pd[hh_], off);
            }
        }
        if (lane == 0) {
            als4[n] = make_float4(ps[0], ps[1], ps[2], ps[3]);
            ald4[n] = make_float4(pd[0], pd[1], pd[2], pd[3]);
        }
    }
}

// ---------------------------------------------------------------------------
// prep_scat: fixed-capacity CSR scatter, 4 edges/thread. NOT idempotent.
// ---------------------------------------------------------------------------
__global__ __launch_bounds__(256) void prep_scat_kernel(const int* __restrict__ edge_index,
                                                        int* __restrict__ degs,
                                                        int* __restrict__ csr_src) {
    int base = blockIdx.x * 1024;
    int tid = threadIdx.x;
#pragma unroll
    for (int k = 0; k < 4; k++) {
        int e = base + k * 256 + tid;
        if (e < E_TOTAL) {
            int s, d;
            if (e < N_EDGES) { s = edge_index[e]; d = edge_index[N_EDGES + e]; }
            else             { s = e - N_EDGES;   d = s; }
            int pos = atomicAdd(&degs[d], 1);
            if (pos < CSR_CAP) csr_src[d * CSR_CAP + pos] = s;
        }
    }
}

// ---------------------------------------------------------------------------
// agg3 (verified R8: 13.2 us/rep; VALUBusy 81%, Occ 67%, VGPR 32 — at the
// VALU issue ceiling for this structure, ~8 inst/edge with 4 pk_fma).
// Phase 1 (lane = edge): exps + butterfly sum + pre-divide -> LDS.
// Phase 2 (per edge): uniform ds_reads + 1 global load + 4 pk_fma.
// ---------------------------------------------------------------------------
template<int LYR, int REPS>
__global__ __launch_bounds__(256) void agg3_kernel(const unsigned short* __restrict__ h_bf,
                                                   const float4* __restrict__ als4,
                                                   const float4* __restrict__ ald4,
                                                   const int* __restrict__ degs,
                                                   const int* __restrict__ csr_src,
                                                   unsigned short* __restrict__ z) {
    __shared__ __align__(16) float wlds[4][CSR_CAP][4];
    __shared__ unsigned olds[4][CSR_CAP];
    int wave = threadIdx.x >> 6, lane = threadIdx.x & 63;
    int n = blockIdx.x * 4 + wave;
    if (n >= N_NODES) return;

    int deg = degs[n];
    deg = (deg < CSR_CAP) ? deg : CSR_CAP;
    const int* __restrict__ srcp = csr_src + (size_t)n * CSR_CAP;
    const unsigned char* __restrict__ hbase = (const unsigned char*)h_bf;
    float4 ad = ald4[n];
    unsigned lane4 = (unsigned)lane * 4u;

#pragma unroll 1
    for (int rep = 0; rep < REPS; ++rep) {
        // ---- phase 1: lane = edge ----
        float4 w4 = make_float4(0.f, 0.f, 0.f, 0.f);
        unsigned off_ = 0;
        if (lane < deg) {
            int s = srcp[lane];                       // coalesced
            off_ = (unsigned)s * 256u;                // byte offset into h_bf row
            float4 as = als4[s];                      // 16B gather, one per edge
            float v;
            v = as.x + ad.x; v = fmaxf(v, NEG_SLOPE * v); w4.x = __expf(fminf(v, 60.f));
            v = as.y + ad.y; v = fmaxf(v, NEG_SLOPE * v); w4.y = __expf(fminf(v, 60.f));
            v = as.z + ad.z; v = fmaxf(v, NEG_SLOPE * v); w4.z = __expf(fminf(v, 60.f));
            v = as.w + ad.w; v = fmaxf(v, NEG_SLOPE * v); w4.w = __expf(fminf(v, 60.f));
        }
        float lsx = w4.x, lsy = w4.y, lsz = w4.z, lsw = w4.w;
#pragma unroll
        for (int o = 32; o; o >>= 1) {
            lsx += __shfl_xor(lsx, o);
            lsy += __shfl_xor(lsy, o);
            lsz += __shfl_xor(lsz, o);
            lsw += __shfl_xor(lsw, o);
        }
        float ix = 1.f / lsx, iy = 1.f / lsy, iz = 1.f / lsz, iw = 1.f / lsw;
        if (lane < deg) {
            wlds[wave][lane][0] = w4.x * ix;
            wlds[wave][lane][1] = w4.y * iy;
            wlds[wave][lane][2] = w4.z * iz;
            wlds[wave][lane][3] = w4.w * iw;
            olds[wave][lane] = off_;
        }
        // ---- phase 2: gather-FMA ----
        f32x2 acc2[4] = {};
        int e = 0;
        for (; e + 4 <= deg; e += 4) {
            unsigned o0 = olds[wave][e];
            unsigned o1 = olds[wave][e + 1];
            unsigned o2 = olds[wave][e + 2];
            unsigned o3 = olds[wave][e + 3];
            unsigned hv0 = *(const unsigned*)(hbase + o0 + lane4);
            unsigned hv1 = *(const unsigned*)(hbase + o1 + lane4);
            unsigned hv2 = *(const unsigned*)(hbase + o2 + lane4);
            unsigned hv3 = *(const unsigned*)(hbase + o3 + lane4);
            float4 w0 = *(const float4*)&wlds[wave][e][0];
            float4 w1 = *(const float4*)&wlds[wave][e + 1][0];
            float4 w2 = *(const float4*)&wlds[wave][e + 2][0];
            float4 w3 = *(const float4*)&wlds[wave][e + 3][0];
            f32x2 f;
            f.x = blo(hv0); f.y = bhi(hv0);
            acc2[0] += w0.x * f; acc2[1] += w0.y * f; acc2[2] += w0.z * f; acc2[3] += w0.w * f;
            f.x = blo(hv1); f.y = bhi(hv1);
            acc2[0] += w1.x * f; acc2[1] += w1.y * f; acc2[2] += w1.z * f; acc2[3] += w1.w * f;
            f.x = blo(hv2); f.y = bhi(hv2);
            acc2[0] += w2.x * f; acc2[1] += w2.y * f; acc2[2] += w2.z * f; acc2[3] += w2.w * f;
            f.x = blo(hv3); f.y = bhi(hv3);
            acc2[0] += w3.x * f; acc2[1] += w3.y * f; acc2[2] += w3.z * f; acc2[3] += w3.w * f;
        }
        for (; e < deg; e++) {
            unsigned o0 = olds[wave][e];
            unsigned hv0 = *(const unsigned*)(hbase + o0 + lane4);
            float4 w0 = *(const float4*)&wlds[wave][e][0];
            f32x2 f;
            f.x = blo(hv0); f.y = bhi(hv0);
            acc2[0] += w0.x * f; acc2[1] += w0.y * f; acc2[2] += w0.z * f; acc2[3] += w0.w * f;
        }
        // ---- epilogue: pack & store (already normalized) ----
        uint4 pb;
        unsigned int* pc = &pb.x;
#pragma unroll
        for (int hh_ = 0; hh_ < 4; hh_++) {
            pc[hh_] = (unsigned)f2b(acc2[hh_].x) | ((unsigned)f2b(acc2[hh_].y) << 16);
        }
        *(uint4*)(z + (size_t)n * 512 + lane * 8) = pb;
    }
}

// ---------------------------------------------------------------------------
// zgemm v2 (verified, BM=64, session-final): out = z[M,512] @ wt2[128,512]^T,
// fused bias + LN + ReLU + bf16 residual + next-layer alpha. 512 thr/8 waves.
// Verified 14.0 us/rep (R5). Structural alternatives FALSIFIED:
//  - BM=32 (R9): +12 us/launch — B-staging is invariant to BM, doubling
//    blocks doubled total staging work in a staging-dominated kernel.
//  - direct-from-L2, no LDS (R12): 49 us — MFMA-fragment gathers split each
//    load into 16x64B segments; at 1.4 waves/SIMD nothing hides the latency.
// LDS staging is what converts fragment layout into coalesced loads; keep it.
// ---------------------------------------------------------------------------
template<int LYR>
__global__ __launch_bounds__(512) void zgemm_kernel(const unsigned short* __restrict__ z,
                                                    const unsigned short* __restrict__ wt2_l,
                                                    const float* __restrict__ b_gat,
                                                    const float* __restrict__ ln_w,
                                                    const float* __restrict__ ln_b,
                                                    const unsigned short* __restrict__ hb_in,
                                                    unsigned short* __restrict__ hb_out,
                                                    const float* __restrict__ q_s_next,
                                                    const float* __restrict__ q_d_next,
                                                    float4* __restrict__ als4,
                                                    float4* __restrict__ ald4,
                                                    int M) {
    __shared__ __align__(16) unsigned short As[64 * 136];
    __shared__ __align__(16) unsigned short Bs[128 * 136];
    __shared__ float redS[2][4][16];
    __shared__ float redQ[2][4][16];
    __shared__ float redPS[2][4][16][4];
    __shared__ float redPD[2][4][16][4];
    int tid = threadIdx.x;
    int m0 = blockIdx.x << 6;
    int wave = tid >> 6, lane = tid & 63;
    int lr = lane & 15, lg = lane >> 4;
    int msub = wave & 3, nh = wave >> 2;

    const uint4 zero4 = make_uint4(0, 0, 0, 0);
    f32x4 acc[4] = {};
    for (int kc = 0; kc < 4; kc++) {
#pragma unroll
        for (int p = 0; p < 2; p++) {        // A: 64 rows x 16 kg (512 thr)
            int i = p * 512 + tid;
            int row = i >> 4, kg = i & 15;
            int arow = m0 + row;
            uint4 av = (arow < M) ? *(const uint4*)(z + (size_t)arow * 512 + kc * 128 + kg * 8) : zero4;
            *(uint4*)&As[row * 136 + kg * 8] = av;
        }
#pragma unroll
        for (int p = 0; p < 4; p++) {        // B: 128 rows x 16 kg (512 thr)
            int i = p * 512 + tid;
            int row = i >> 4, kg = i & 15;
            uint4 bv = *(const uint4*)(wt2_l + (size_t)row * 512 + kc * 128 + kg * 8);
            *(uint4*)&Bs[row * 136 + kg * 8] = bv;
        }
        __syncthreads();
#pragma unroll
        for (int ks = 0; ks < 4; ks++) {
            bf16x8 af = *(const bf16x8*)&As[(msub * 16 + lr) * 136 + ks * 32 + lg * 8];
#pragma unroll
            for (int nt2 = 0; nt2 < 4; nt2++) {
                int nt = nh * 4 + nt2;
                bf16x8 bf_ = *(const bf16x8*)&Bs[(nt * 16 + lr) * 136 + ks * 32 + lg * 8];
                acc[nt2] = __builtin_amdgcn_mfma_f32_16x16x32_bf16(af, bf_, acc[nt2], 0, 0, 0);
            }
        }
        __syncthreads();
    }

    // ---- epilogue: bias + LN (cross-half LDS reduce) + relu + residual ----
    float bg[4], lnw[4], lnb[4];
#pragma unroll
    for (int nt2 = 0; nt2 < 4; nt2++) {
        int col = nh * 64 + nt2 * 16 + lr;
        bg[nt2] = b_gat[col]; lnw[nt2] = ln_w[col]; lnb[nt2] = ln_b[col];
    }
    const bool do_alpha = (LYR + 1 < NLAYER);
    float4 qs4[4], qd4[4];
    if (do_alpha) {
#pragma unroll
        for (int nt2 = 0; nt2 < 4; nt2++) {
            int col = nh * 64 + nt2 * 16 + lr;
            qs4[nt2] = *(const float4*)(q_s_next + (size_t)col * 4);
            qd4[nt2] = *(const float4*)(q_d_next + (size_t)col * 4);
        }
    }
    float g[4][4];                       // [nt2][r]
#pragma unroll
    for (int nt2 = 0; nt2 < 4; nt2++)
#pragma unroll
        for (int r = 0; r < 4; r++) g[nt2][r] = acc[nt2][r] + bg[nt2];
#pragma unroll
    for (int r = 0; r < 4; r++) {
        float s = 0.f, q = 0.f;
#pragma unroll
        for (int nt2 = 0; nt2 < 4; nt2++) { s += g[nt2][r]; q += g[nt2][r] * g[nt2][r]; }
#pragma unroll
        for (int off = 1; off < 16; off <<= 1) { s += __shfl_xor(s, off); q += __shfl_xor(q, off); }
        if (lr == 0) { redS[nh][msub][lg * 4 + r] = s; redQ[nh][msub][lg * 4 + r] = q; }
    }
    __syncthreads();
    float o[4][4];
#pragma unroll
    for (int r = 0; r < 4; r++) {
        int row = m0 + msub * 16 + lg * 4 + r;
        bool valid = (row < M);
        int ri = lg * 4 + r;
        float mu = (redS[0][msub][ri] + redS[1][msub][ri]) * (1.f / 128.f);
        float qq = (redQ[0][msub][ri] + redQ[1][msub][ri]) * (1.f / 128.f);
        float rstd = rsqrtf(fmaxf(qq - mu * mu, 0.f) + LN_EPS);
#pragma unroll
        for (int nt2 = 0; nt2 < 4; nt2++) {
            int col = nh * 64 + nt2 * 16 + lr;
            float hv = valid ? b2f(hb_in[(size_t)row * 128 + col]) : 0.f;
            o[nt2][r] = fmaxf((g[nt2][r] - mu) * rstd * lnw[nt2] + lnb[nt2], 0.f) + hv;
            if (valid) hb_out[(size_t)row * 128 + col] = f2b(o[nt2][r]);
        }
    }
    if (do_alpha) {
        float ps[4][4] = {}, pd[4][4] = {};   // [r][h]
#pragma unroll
        for (int r = 0; r < 4; r++)
#pragma unroll
            for (int nt2 = 0; nt2 < 4; nt2++) {
                ps[r][0] += o[nt2][r] * qs4[nt2].x; pd[r][0] += o[nt2][r] * qd4[nt2].x;
                ps[r][1] += o[nt2][r] * qs4[nt2].y; pd[r][1] += o[nt2][r] * qd4[nt2].y;
                ps[r][2] += o[nt2][r] * qs4[nt2].z; pd[r][2] += o[nt2][r] * qd4[nt2].z;
                ps[r][3] += o[nt2][r] * qs4[nt2].w; pd[r][3] += o[nt2][r] * qd4[nt2].w;
            }
#pragma unroll
        for (int r = 0; r < 4; r++)
#pragma unroll
            for (int off = 1; off < 16; off <<= 1)
#pragma unroll
                for (int hh_ = 0; hh_ < 4; hh_++) {
                    ps[r][hh_] += __shfl_xor(ps[r][hh_], off);
                    pd[r][hh_] += __shfl_xor(pd[r][hh_], off);
                }
        if (lr == 0) {
#pragma unroll
            for (int r = 0; r < 4; r++)
#pragma unroll
                for (int hh_ = 0; hh_ < 4; hh_++) {
                    redPS[nh][msub][lg * 4 + r][hh_] = ps[r][hh_];
                    redPD[nh][msub][lg * 4 + r][hh_] = pd[r][hh_];
                }
        }
        __syncthreads();
        if (nh == 0 && lr == 0) {
#pragma unroll
            for (int r = 0; r < 4; r++) {
                int row = m0 + msub * 16 + lg * 4 + r;
                int ri = lg * 4 + r;
                if (row < M) {
                    als4[row] = make_float4(redPS[0][msub][ri][0] + redPS[1][msub][ri][0],
                                            redPS[0][msub][ri][1] + redPS[1][msub][ri][1],
                                            redPS[0][msub][ri][2] + redPS[1][msub][ri][2],
                                            redPS[0][msub][ri][3] + redPS[1][msub][ri][3]);
                    ald4[row] = make_float4(redPD[0][msub][ri][0] + redPD[1][msub][ri][0],
                                            redPD[0][msub][ri][1] + redPD[1][msub][ri][1],
                                            redPD[0][msub][ri][2] + redPD[1][msub][ri][2],
                                            redPD[0][msub][ri][3] + redPD[1][msub][ri][3]);
                }
            }
        }
    }
}

// ---------------------------------------------------------------------------
// pool4: per-graph pooling split 4 ways — block (g,q4) computes partial
// sum/max over its quarter of graph g's nodes.
// ---------------------------------------------------------------------------
__device__ int lower_bound_dev(const int* a, int n, int v) {
    int lo = 0, hi = n;
    while (lo < hi) { int mid = (lo + hi) >> 1; if (a[mid] < v) lo = mid + 1; else hi = mid; }
    return lo;
}

__global__ __launch_bounds__(256) void pool4_kernel(const unsigned short* __restrict__ h,
                                                    const int* __restrict__ batch,
                                                    float* __restrict__ pool_ws) {
    int g = blockIdx.x >> 2, q4 = blockIdx.x & 3;
    int tid = threadIdx.x;
    __shared__ int bounds[2];
    __shared__ float psum[2][128];
    __shared__ float pmax[2][128];
    if (tid < 2) bounds[tid] = lower_bound_dev(batch, N_NODES, g + tid);
    __syncthreads();
    int lo = bounds[0], hi = bounds[1];
    int cnt = hi - lo;
    int per = (cnt + 3) >> 2;
    int beg = lo + q4 * per;
    int end = min(beg + per, hi);
    int rq = tid >> 7, d = tid & 127;
    float s = 0.f, m = -1e30f;
    for (int i = beg + rq; i < end; i += 2) {
        float v = b2f(h[(size_t)i * DIM + d]);
        s += v; m = fmaxf(m, v);
    }
    psum[rq][d] = s; pmax[rq][d] = m;
    __syncthreads();
    if (tid < 128) {
        float S = psum[0][d] + psum[1][d];
        float M = fmaxf(pmax[0][d], pmax[1][d]);
        pool_ws[(((size_t)g * 4 + q4) * 2 + 0) * 128 + d] = S;
        pool_ws[(((size_t)g * 4 + q4) * 2 + 1) * 128 + d] = M;
    }
}

// ---------------------------------------------------------------------------
// tail: per-graph MLP tail; pooling phase reads the 4 partials from pool_ws.
// ---------------------------------------------------------------------------
__global__ __launch_bounds__(512) void tail_kernel(
    const float* __restrict__ pool_ws, const int* __restrict__ batch,
    const float* __restrict__ tda,
    const float* __restrict__ w_t1, const float* __restrict__ b_t1,
    const float* __restrict__ w_t2, const float* __restrict__ b_t2,
    const float* __restrict__ w_sh1, const float* __restrict__ b_sh1,
    const float* __restrict__ w_sh2, const float* __restrict__ b_sh2,
    const float* __restrict__ w_h1, const float* __restrict__ b_h1,
    const float* __restrict__ w_h2, const float* __restrict__ b_h2,
    float* __restrict__ out) {
    __shared__ int bounds[2];
    __shared__ float comb[320];
    __shared__ float tr[F_TDA];
    __shared__ float t1[64];
    __shared__ float s1o[256];
    __shared__ float s2o[128];
    __shared__ float prods[NTASK * 64];
    int g = blockIdx.x, tid = threadIdx.x;

    if (tid < 2) bounds[tid] = lower_bound_dev(batch, N_NODES, g + tid);
    if (tid >= 2 && tid - 2 < F_TDA) tr[tid - 2] = tda[g * F_TDA + (tid - 2)];
    __syncthreads();
    int cnt = bounds[1] - bounds[0];
    if (tid < 128) {
        float S = 0.f, M = -1e30f;
#pragma unroll
        for (int q4 = 0; q4 < 4; q4++) {
            S += pool_ws[(((size_t)g * 4 + q4) * 2 + 0) * 128 + tid];
            M = fmaxf(M, pool_ws[(((size_t)g * 4 + q4) * 2 + 1) * 128 + tid]);
        }
        comb[tid] = S / fmaxf((float)cnt, 1.f);
        comb[128 + tid] = (cnt > 0) ? M : 0.f;
    } else if (tid >= 128 && tid < 192) {
        int j = tid - 128;
        float a = b_t1[j];
#pragma unroll
        for (int k = 0; k < F_TDA; k++) a += tr[k] * w_t1[k * 64 + j];
        t1[j] = fmaxf(a, 0.f);
    }
    __syncthreads();
    if (tid < 64) {
        float a = b_t2[tid];
#pragma unroll
        for (int k = 0; k < 64; k++) a += t1[k] * w_t2[k * 64 + tid];
        comb[256 + tid] = fmaxf(a, 0.f);
    }
    __syncthreads();
    if (tid < 256) {
        float a = b_sh1[tid];
        for (int k = 0; k < 320; k++) a += comb[k] * w_sh1[k * 256 + tid];
        s1o[tid] = fmaxf(a, 0.f);
    }
    __syncthreads();
    if (tid < 128) {
        float a = b_sh2[tid];
        for (int k = 0; k < 256; k++) a += s1o[k] * w_sh2[k * 128 + tid];
        s2o[tid] = fmaxf(a, 0.f);
    }
    __syncthreads();
    if (tid < NTASK * 64) {
        int t = tid >> 6, k = tid & 63;
        float a = b_h1[t * 64 + k];
#pragma unroll 16
        for (int dd = 0; dd < 128; dd++) a += s2o[dd] * w_h1[(size_t)t * 8192 + dd * 64 + k];
        prods[tid] = fmaxf(a, 0.f) * w_h2[t * 64 + k];
    }
    __syncthreads();
    if (tid < NTASK) {
        float p = b_h2[tid];
#pragma unroll 16
        for (int k = 0; k < 64; k++) p += prods[tid * 64 + k];
        out[tid * 256 + g] = p;
    }
}

// ---------------------------------------------------------------------------
extern "C" void kernel_launch(void* const* d_in, const int* in_sizes, int n_in,
                              void* d_out, int out_size, void* d_ws, size_t ws_size,
                              hipStream_t stream) {
    const float* x        = (const float*)d_in[0];
    const int*   edge_idx = (const int*)  d_in[1];
    const int*   batch    = (const int*)  d_in[2];
    const float* tda      = (const float*)d_in[3];
    const float* w_in     = (const float*)d_in[4];
    const float* b_in     = (const float*)d_in[5];
    const float* w_gat    = (const float*)d_in[6];
    const float* a_src    = (const float*)d_in[7];
    const float* a_dst    = (const float*)d_in[8];
    const float* b_gat    = (const float*)d_in[9];
    const float* ln_w     = (const float*)d_in[10];
    const float* ln_b     = (const float*)d_in[11];
    const float* w_tda1   = (const float*)d_in[12];
    const float* b_tda1   = (const float*)d_in[13];
    const float* w_tda2   = (const float*)d_in[14];
    const float* b_tda2   = (const float*)d_in[15];
    const float* w_sh1    = (const float*)d_in[16];
    const float* b_sh1    = (const float*)d_in[17];
    const float* w_sh2    = (const float*)d_in[18];
    const float* b_sh2    = (const float*)d_in[19];
    const float* w_h1     = (const float*)d_in[20];
    const float* b_h1     = (const float*)d_in[21];
    const float* w_h2     = (const float*)d_in[22];
    const float* b_h2     = (const float*)d_in[23];
    float* out = (float*)d_out;

    size_t off = 0;
    auto alloc = [&](size_t bytes) -> void* {
        void* p = (char*)d_ws + off;
        off += (bytes + 255) & ~(size_t)255;
        return p;
    };
    unsigned short* hb_a   = (unsigned short*)alloc((size_t)N_NODES * DIM * 2);
    unsigned short* hb_b   = (unsigned short*)alloc((size_t)N_NODES * DIM * 2);
    unsigned short* z      = (unsigned short*)alloc((size_t)N_NODES * 512 * 2);
    unsigned short* wt2    = (unsigned short*)alloc((size_t)NLAYER * 128 * 512 * 2);
    float*          q_s    = (float*)alloc((size_t)NLAYER * 128 * 4 * 4);
    float*          q_d    = (float*)alloc((size_t)NLAYER * 128 * 4 * 4);
    float4*         als4   = (float4*)alloc((size_t)N_NODES * 16);
    float4*         ald4   = (float4*)alloc((size_t)N_NODES * 16);
    int*            degs   = (int*)  alloc((size_t)N_NODES * 4);
    int*            csrsrc = (int*)  alloc((size_t)N_NODES * CSR_CAP * 4);
    float*          poolws = (float*)alloc((size_t)N_GRAPHS * 4 * 2 * 128 * 4);

    // qprep also zeroes degs (blocks 1152..1171) — no separate memset
    qprep_kernel<<<1172, 256, 0, stream>>>(w_gat, a_src, a_dst, wt2, q_s, q_d, degs);

    prep_proj_kernel<<<2500, 256, 0, stream>>>(x, w_in, b_in, hb_a, q_s, q_d, als4, ald4);
    int sb = (E_TOTAL + 1023) / 1024;   // 333
    prep_scat_kernel<<<sb, 256, 0, stream>>>(edge_idx, degs, csrsrc);

    int ab = (N_NODES + 3) / 4;
    int gb = (N_NODES + 63) / 64;        // 313 blocks (BM=64, verified v2)
    // layer 0: hb_a -> hb_b
    agg3_kernel<0, 1><<<ab, 256, 0, stream>>>(hb_a, als4, ald4, degs, csrsrc, z);
    zgemm_kernel<0><<<gb, 512, 0, stream>>>(z, wt2,
        b_gat, ln_w, ln_b, hb_a, hb_b, q_s + 512, q_d + 512, als4, ald4, N_NODES);
    // layer 1: hb_b -> hb_a
    agg3_kernel<1, 1><<<ab, 256, 0, stream>>>(hb_b, als4, ald4, degs, csrsrc, z);
    zgemm_kernel<1><<<gb, 512, 0, stream>>>(z, wt2 + 65536,
        b_gat + DIM, ln_w + DIM, ln_b + DIM, hb_b, hb_a, q_s + 1024, q_d + 1024,
        als4, ald4, N_NODES);
    // layer 2: hb_a -> hb_b
    agg3_kernel<2, 1><<<ab, 256, 0, stream>>>(hb_a, als4, ald4, degs, csrsrc, z);
    zgemm_kernel<2><<<gb, 512, 0, stream>>>(z, wt2 + 131072,
        b_gat + 2 * DIM, ln_w + 2 * DIM, ln_b + 2 * DIM, hb_a, hb_b,
        nullptr, nullptr, als4, ald4, N_NODES);

    pool4_kernel<<<N_GRAPHS * 4, 256, 0, stream>>>(hb_b, batch, poolws);
    tail_kernel<<<N_GRAPHS, 512, 0, stream>>>(
        poolws, batch, tda, w_tda1, b_tda1, w_tda2, b_tda2,
        w_sh1, b_sh1, w_sh2, b_sh2, w_h1, b_h1, w_h2, b_h2, out);
}